// Round 21
// baseline (132.144 us; speedup 1.0000x reference)
//
#include <hip/hip_runtime.h>
#include <math.h>

#define BATCH  2
#define SEQ    1024
#define HIDDEN 1024
#define NHEADS 8
#define DHEAD  128
#define NTOK   (BATCH*SEQ)
#define GEPS   1e-5f

typedef float f32x16 __attribute__((ext_vector_type(16)));
typedef __bf16 bf16x8 __attribute__((ext_vector_type(8)));
typedef unsigned int u32x4 __attribute__((ext_vector_type(4)));
typedef unsigned int u32x2 __attribute__((ext_vector_type(2)));

union Frag { u32x4 u; bf16x8 h; };

__device__ __forceinline__ unsigned short f2bf(float f) {
    unsigned int u = __float_as_uint(f);
    unsigned int r = (u + 0x7FFFu + ((u >> 16) & 1u)) >> 16;
    return (unsigned short)r;
}
__device__ __forceinline__ float bf2f(unsigned short u) {
    return __uint_as_float(((unsigned int)u) << 16);
}

// complex swish: z * sigmoid(z)
__device__ __forceinline__ void cswish(float zr, float zi, float& outr, float& outi) {
    const float e = expf(-zr);
    float sg, cg;
    sincosf(zi, &sg, &cg);
    const float wr = fmaf(e, cg, 1.0f);
    const float wi = -e*sg;
    const float inv = 1.0f / fmaf(wr, wr, wi*wi);
    outr = (zr*wr + zi*wi)*inv;
    outi = (zi*wr - zr*wi)*inv;
}

// ---------------------------------------------------------------------------
// merged prep kernel (unchanged)
// ---------------------------------------------------------------------------
__global__ __launch_bounds__(256) void prep_kernel(
    const float* __restrict__ X,
    const float* __restrict__ Wq, const float* __restrict__ Wk, const float* __restrict__ Wv,
    const float* __restrict__ Wgre, const float* __restrict__ Wgim,
    const float* __restrict__ Wore, const float* __restrict__ Woim,
    float* __restrict__ gpow, unsigned short* __restrict__ Xb,
    unsigned short* __restrict__ Wt, unsigned short* __restrict__ Bg,
    unsigned short* __restrict__ Bot)
{
    __shared__ float Ws[64][65];
    const int id  = blockIdx.x;
    const int tid = threadIdx.x;

    if (id < 32) {
        const int h = id >> 2;
        const int k = (id & 3)*256 + tid;
        const float l = fmaf((float)h, -0.39608410317711170f, -3.46573590279972650f);
        const float gamma = 1.0f - expf(l);
        gpow[h*SEQ + k] = powf(gamma, (float)k);
    } else if (id < 1056) {
        const size_t i = ((size_t)(id - 32)*256 + tid)*8;
        const float4 a = *(const float4*)&X[i];
        const float4 b = *(const float4*)&X[i+4];
        __align__(16) unsigned short t[8] = { f2bf(a.x), f2bf(a.y), f2bf(a.z), f2bf(a.w),
                                              f2bf(b.x), f2bf(b.y), f2bf(b.z), f2bf(b.w) };
        *(u32x4*)&Xb[i] = *(u32x4*)t;
    } else if (id < 1152) {
        const int q = id - 1056;
        const int th_ = q % 24, yy = q / 24;
        const int type = th_ >> 3, h = th_ & 7;
        const int k0 = (yy >> 1)*64, n0 = (yy & 1)*64;
        const float* W = ((type == 0) ? Wq : (type == 1) ? Wk : Wv)
                         + (size_t)h*DHEAD*DHEAD;
        #pragma unroll
        for (int it = 0; it < 4; ++it) {
            const int r = (tid >> 4) + it*16, c = (tid & 15)*4;
            *(float4*)&Ws[r][c] = *(const float4*)&W[(size_t)(k0 + r)*DHEAD + n0 + c];
        }
        __syncthreads();
        const int nl = tid >> 2, seg = (tid & 3)*16;
        __align__(16) unsigned short t[16];
        #pragma unroll
        for (int j = 0; j < 16; ++j) t[j] = f2bf(Ws[seg + j][nl]);
        u32x4* d = (u32x4*)&Wt[((size_t)th_*DHEAD + n0 + nl)*DHEAD + k0 + seg];
        d[0] = ((u32x4*)t)[0];
        d[1] = ((u32x4*)t)[1];
    } else if (id < 1664) {
        const int q = id - 1152;
        const int xx = q & 31, k0 = (q >> 5)*64;
        const int plane = xx >> 4;
        const int c0 = (xx & 15)*64;
        const float* src = plane ? Wgim : Wgre;
        #pragma unroll
        for (int it = 0; it < 4; ++it) {
            const int r = (tid >> 4) + it*16, c = (tid & 15)*4;
            *(float4*)&Ws[r][c] = *(const float4*)&src[(size_t)(k0 + r)*HIDDEN + c0 + c];
        }
        __syncthreads();
        const int nl = tid >> 2, seg = (tid & 3)*16;
        __align__(16) unsigned short t[16];
        #pragma unroll
        for (int j = 0; j < 16; ++j) t[j] = f2bf(Ws[seg + j][nl]);
        u32x4* d = (u32x4*)&Bg[((size_t)plane << 20) + (size_t)(c0 + nl)*HIDDEN + k0 + seg];
        d[0] = ((u32x4*)t)[0];
        d[1] = ((u32x4*)t)[1];
    } else {
        const int q = id - 1664;
        const int n0 = (q & 15)*64, k0 = (q >> 4)*64;
        const float* src;
        float sign = 1.0f;
        if (k0 < HIDDEN) src = Wore; else { src = Woim; sign = -1.0f; }
        const int kc = k0 & (HIDDEN-1);
        #pragma unroll
        for (int it = 0; it < 4; ++it) {
            const int r = (tid >> 4) + it*16, c = (tid & 15)*4;
            const float4 v = *(const float4*)&src[(size_t)(kc + r)*HIDDEN + n0 + c];
            Ws[r][c+0] = v.x*sign; Ws[r][c+1] = v.y*sign; Ws[r][c+2] = v.z*sign; Ws[r][c+3] = v.w*sign;
        }
        __syncthreads();
        const int nl = tid >> 2, seg = (tid & 3)*16;
        __align__(16) unsigned short t[16];
        #pragma unroll
        for (int j = 0; j < 16; ++j) t[j] = f2bf(Ws[seg + j][nl]);
        u32x4* d = (u32x4*)&Bot[(size_t)(n0 + nl)*(2*HIDDEN) + k0 + seg];
        d[0] = ((u32x4*)t)[0];
        d[1] = ((u32x4*)t)[1];
    }
}

// ---------------------------------------------------------------------------
// MFMA projections + fused RoPE (unchanged)
// ---------------------------------------------------------------------------
__global__ __launch_bounds__(256) void projm_kernel(
    const unsigned short* __restrict__ Xb,
    const unsigned short* __restrict__ Wt,
    const float* __restrict__ theta,
    unsigned short* __restrict__ Qbre, unsigned short* __restrict__ Qbim,
    unsigned short* __restrict__ Kbre, unsigned short* __restrict__ Kbim,
    unsigned short* __restrict__ Vtb)
{
    const int tt = blockIdx.x;
    const int h  = blockIdx.y;
    const int mt = blockIdx.z;       // 0:q 1:k 2:v
    const int tid = threadIdx.x;
    const int w = tid >> 6, lane = tid & 63;
    const int th = w >> 1, nh = w & 1;
    const int l31 = lane & 31, hi = (lane >> 5) & 1;

    Frag A[8];
    {
        const unsigned short* xa = Xb + (size_t)(tt*64 + th*32 + l31)*HIDDEN
                                   + h*DHEAD + 8*hi;
        #pragma unroll
        for (int ks = 0; ks < 8; ++ks) A[ks].u = *(const u32x4*)(xa + 16*ks);
    }

    const unsigned short* wb = Wt + (size_t)(mt*NHEADS + h)*DHEAD*DHEAD;

    #pragma unroll
    for (int nt = 0; nt < 2; ++nt) {
        const int n0 = nh*64 + nt*32;
        const int n  = n0 + l31;

        Frag B[8];
        const unsigned short* wp = wb + (size_t)n*DHEAD + 8*hi;
        #pragma unroll
        for (int ks = 0; ks < 8; ++ks) B[ks].u = *(const u32x4*)(wp + 16*ks);

        f32x16 acc;
        #pragma unroll
        for (int e = 0; e < 16; ++e) acc[e] = 0.f;
        #pragma unroll
        for (int ks = 0; ks < 8; ++ks)
            acc = __builtin_amdgcn_mfma_f32_32x32x16_bf16(A[ks].h, B[ks].h, acc, 0, 0, 0);

        if (mt == 2) {
            const int b2  = (tt*64) >> 10;
            const int bh2 = b2*NHEADS + h;
            const int sbase = (tt*64 + th*32) & (SEQ-1);
            unsigned short* vdst = Vtb + ((size_t)(bh2*DHEAD + n))*SEQ + sbase;
            #pragma unroll
            for (int g2 = 0; g2 < 4; ++g2) {
                const int s0 = 8*g2 + 4*hi;
                __align__(8) unsigned short t4[4];
                #pragma unroll
                for (int j = 0; j < 4; ++j) t4[j] = f2bf(acc[g2*4 + j]);
                *(u32x2*)(vdst + s0) = *(u32x2*)t4;
            }
        } else {
            const float thv = theta[h*DHEAD + n];
            unsigned short* pre = (mt == 0) ? Qbre : Kbre;
            unsigned short* pim = (mt == 0) ? Qbim : Kbim;
            const float sgn = (mt == 0) ? 1.0f : -1.0f;
            #pragma unroll
            for (int r = 0; r < 16; ++r) {
                const int row = (r & 3) + 8*(r >> 2) + 4*hi;
                const int tok = tt*64 + th*32 + row;
                const float np1 = (float)((tok & (SEQ-1)) + 1);
                float s, c;
                sincosf(np1*thv, &s, &c);
                const size_t g = (size_t)tok*HIDDEN + h*DHEAD + n;
                pre[g] = f2bf(acc[r]*c);
                pim[g] = f2bf(acc[r]*s*sgn);
            }
        }
    }
}

// ---------------------------------------------------------------------------
// FAT kernel (256 threads, 4 waves):
//   blocks [0,256)   = attention pair (qt=j, qt=31-j), 4-way m-split per tile,
//                      uniform ~8.25 iters/wave -> no straggler tail.
//   blocks [256,768) = gating GEMM 64x64 tile, 4 waves of 32x32x2planes.
// Grid 768 > capacity (2 blk/CU) -> 256-block backfill queue.
// ---------------------------------------------------------------------------
#define CVTPK(dst, a, b) asm("v_cvt_pk_bf16_f32 %0, %1, %2" : "=v"(dst) : "v"(a), "v"(b))
#define SWAP32(x, y)     asm("v_permlane32_swap_b32 %0, %1" : "+v"(x), "+v"(y))

union FatLds {
    struct { float Ytr[32][133]; float Yti[32][133]; } a;
    struct { unsigned short As[64][68]; unsigned short Br[64][68]; unsigned short Bi[64][68]; } g;
};

__global__ __launch_bounds__(256) void fat_kernel(
    const unsigned short* __restrict__ Qbre, const unsigned short* __restrict__ Qbim,
    const unsigned short* __restrict__ Kbre, const unsigned short* __restrict__ Kbim,
    const unsigned short* __restrict__ Vtb,  const float* __restrict__ gpow,
    const float* __restrict__ gnw, const float* __restrict__ gnb,
    unsigned short* __restrict__ Yn,
    const unsigned short* __restrict__ Xb, const unsigned short* __restrict__ Bg,
    unsigned short* __restrict__ Gs)
{
    __shared__ FatLds lds;

    const int bid  = blockIdx.x;
    const int tid  = threadIdx.x;
    const int lane = tid & 63;
    const int wv   = tid >> 6;           // 0..3
    const int l31 = lane & 31, hi = (lane >> 5) & 1;

    if (bid < 256) {
        // ---------------- attention pair path ----------------
        const int bh = ((bid & 7) << 1) | ((bid >> 3) & 1);
        const int j  = bid >> 4;          // 0..15
        const int b = bh >> 3, h = bh & 7;
        const size_t bhoff = (size_t)b*SEQ*HIDDEN + h*DHEAD;
        const float* gp = gpow + h*SEQ;

        int   crw[16];
        float ginv[16];
        #pragma unroll
        for (int r = 0; r < 16; ++r) {
            const int cr = (r & 3) + 8*(r >> 2) + 4*hi;
            crw[r] = cr;
            ginv[r] = 1.0f / gp[cr];
        }

        #pragma unroll 1
        for (int tile = 0; tile < 2; ++tile) {
            const int qt = tile ? (31 - j) : j;
            const int q0 = qt * 32;

            Frag Qr[8], Qi[8];
            {
                const unsigned short* qr = Qbre + bhoff + (size_t)(q0 + l31)*HIDDEN + 8*hi;
                const unsigned short* qi = Qbim + bhoff + (size_t)(q0 + l31)*HIDDEN + 8*hi;
                #pragma unroll
                for (int ks = 0; ks < 8; ++ks) {
                    Qr[ks].u = *(const u32x4*)(qr + 16*ks);
                    Qi[ks].u = *(const u32x4*)(qi + 16*ks);
                }
            }

            f32x16 Yr[4], Yi[4];
            #pragma unroll
            for (int dt = 0; dt < 4; ++dt)
                #pragma unroll
                for (int e = 0; e < 16; ++e) { Yr[dt][e] = 0.f; Yi[dt][e] = 0.f; }

            const int nm  = qt + 1;
            const int mlo = (nm * wv) >> 2;
            const int mhi = (nm * (wv + 1)) >> 2;

            // K single-buffer with early reload
            Frag Kr[8], Ki[8];
            if (mlo < mhi) {
                const int kv0p = mlo*32;
                const unsigned short* kr_ = Kbre + bhoff + (size_t)(kv0p + l31)*HIDDEN + 8*hi;
                const unsigned short* ki_ = Kbim + bhoff + (size_t)(kv0p + l31)*HIDDEN + 8*hi;
                #pragma unroll
                for (int ks = 0; ks < 8; ++ks) {
                    Kr[ks].u = *(const u32x4*)(kr_ + 16*ks);
                    Ki[ks].u = *(const u32x4*)(ki_ + 16*ks);
                }
            }

            #pragma unroll 1
            for (int m = mlo; m < mhi; ++m) {
                const int kv0 = m*32;

                Frag Vf[4][2];
                #pragma unroll
                for (int dt = 0; dt < 4; ++dt)
                    #pragma unroll
                    for (int ks2 = 0; ks2 < 2; ++ks2)
                        Vf[dt][ks2].u = *(const u32x4*)(Vtb + ((size_t)(bh*DHEAD + dt*32 + l31))*SEQ
                                                        + kv0 + 16*ks2 + 8*hi);

                const int  base = 32*(qt - m) + l31;
                const float g1  = gp[base];

                f32x16 SR, SI;
                #pragma unroll
                for (int e = 0; e < 16; ++e) { SR[e] = 0.f; SI[e] = 0.f; }
                #pragma unroll
                for (int ks = 0; ks < 8; ++ks) {
                    Frag Qin;
                    #pragma unroll
                    for (int e = 0; e < 4; ++e) Qin.u[e] = Qi[ks].u[e] ^ 0x80008000u;
                    SR = __builtin_amdgcn_mfma_f32_32x32x16_bf16(Kr[ks].h, Qr[ks].h, SR, 0, 0, 0);
                    SI = __builtin_amdgcn_mfma_f32_32x32x16_bf16(Kr[ks].h, Qi[ks].h, SI, 0, 0, 0);
                    SR = __builtin_amdgcn_mfma_f32_32x32x16_bf16(Ki[ks].h, Qin.h, SR, 0, 0, 0);
                    SI = __builtin_amdgcn_mfma_f32_32x32x16_bf16(Ki[ks].h, Qr[ks].h, SI, 0, 0, 0);
                }

                // K regs dead: reload for m+1 now (latency hides under P+PV)
                if (m + 1 < mhi) {
                    const int kn = (m + 1)*32;
                    const unsigned short* kr_ = Kbre + bhoff + (size_t)(kn + l31)*HIDDEN + 8*hi;
                    const unsigned short* ki_ = Kbim + bhoff + (size_t)(kn + l31)*HIDDEN + 8*hi;
                    #pragma unroll
                    for (int ks = 0; ks < 8; ++ks) {
                        Kr[ks].u = *(const u32x4*)(kr_ + 16*ks);
                        Ki[ks].u = *(const u32x4*)(ki_ + 16*ks);
                    }
                }

                float pr[16], pi[16];
                #pragma unroll
                for (int r = 0; r < 16; ++r) {
                    const float w = (base >= crw[r]) ? g1*ginv[r] : 0.0f;
                    pr[r] = SR[r]*w;
                    pi[r] = SI[r]*w;
                }

                Frag PR[2], PI[2];
                #pragma unroll
                for (int ks2 = 0; ks2 < 2; ++ks2) {
                    const int o = ks2*8;
                    unsigned int a0, b0, a1, b1;
                    CVTPK(a0, pr[o+0], pr[o+1]);
                    CVTPK(b0, pr[o+4], pr[o+5]);
                    SWAP32(a0, b0);
                    CVTPK(a1, pr[o+2], pr[o+3]);
                    CVTPK(b1, pr[o+6], pr[o+7]);
                    SWAP32(a1, b1);
                    PR[ks2].u[0] = a0; PR[ks2].u[1] = a1; PR[ks2].u[2] = b0; PR[ks2].u[3] = b1;
                    CVTPK(a0, pi[o+0], pi[o+1]);
                    CVTPK(b0, pi[o+4], pi[o+5]);
                    SWAP32(a0, b0);
                    CVTPK(a1, pi[o+2], pi[o+3]);
                    CVTPK(b1, pi[o+6], pi[o+7]);
                    SWAP32(a1, b1);
                    PI[ks2].u[0] = a0; PI[ks2].u[1] = a1; PI[ks2].u[2] = b0; PI[ks2].u[3] = b1;
                }

                #pragma unroll
                for (int dt = 0; dt < 4; ++dt) {
                    Yr[dt] = __builtin_amdgcn_mfma_f32_32x32x16_bf16(Vf[dt][0].h, PR[0].h, Yr[dt], 0, 0, 0);
                    Yr[dt] = __builtin_amdgcn_mfma_f32_32x32x16_bf16(Vf[dt][1].h, PR[1].h, Yr[dt], 0, 0, 0);
                    Yi[dt] = __builtin_amdgcn_mfma_f32_32x32x16_bf16(Vf[dt][0].h, PI[0].h, Yi[dt], 0, 0, 0);
                    Yi[dt] = __builtin_amdgcn_mfma_f32_32x32x16_bf16(Vf[dt][1].h, PI[1].h, Yi[dt], 0, 0, 0);
                }
            }

            // 4-stage combine (barrier protects LDS reuse from prior epilogue)
            __syncthreads();
            if (wv == 0) {
                #pragma unroll
                for (int dt = 0; dt < 4; ++dt)
                    #pragma unroll
                    for (int r = 0; r < 16; ++r) {
                        lds.a.Ytr[l31][dt*32 + crw[r]] = Yr[dt][r];
                        lds.a.Yti[l31][dt*32 + crw[r]] = Yi[dt][r];
                    }
            }
            __syncthreads();
            if (wv == 1) {
                #pragma unroll
                for (int dt = 0; dt < 4; ++dt)
                    #pragma unroll
                    for (int r = 0; r < 16; ++r) {
                        lds.a.Ytr[l31][dt*32 + crw[r]] += Yr[dt][r];
                        lds.a.Yti[l31][dt*32 + crw[r]] += Yi[dt][r];
                    }
            }
            __syncthreads();
            if (wv == 2) {
                #pragma unroll
                for (int dt = 0; dt < 4; ++dt)
                    #pragma unroll
                    for (int r = 0; r < 16; ++r) {
                        lds.a.Ytr[l31][dt*32 + crw[r]] += Yr[dt][r];
                        lds.a.Yti[l31][dt*32 + crw[r]] += Yi[dt][r];
                    }
            }
            __syncthreads();
            if (wv == 3) {
                #pragma unroll
                for (int dt = 0; dt < 4; ++dt)
                    #pragma unroll
                    for (int r = 0; r < 16; ++r) {
                        lds.a.Ytr[l31][dt*32 + crw[r]] += Yr[dt][r];
                        lds.a.Yti[l31][dt*32 + crw[r]] += Yi[dt][r];
                    }
            }
            __syncthreads();

            // fused complex group-norm: 8 threads per token row (256 thr)
            {
                const int row = tid >> 3;      // 0..31
                const int q8  = tid & 7;       // cols [q8*16, q8*16+16)
                float sr = 0.f, si = 0.f;
                #pragma unroll 8
                for (int i = 0; i < 16; ++i) {
                    sr += lds.a.Ytr[row][q8*16 + i];
                    si += lds.a.Yti[row][q8*16 + i];
                }
                sr += __shfl_xor(sr, 1); sr += __shfl_xor(sr, 2); sr += __shfl_xor(sr, 4);
                si += __shfl_xor(si, 1); si += __shfl_xor(si, 2); si += __shfl_xor(si, 4);
                const float mr = sr * (1.0f/128.0f), mi = si * (1.0f/128.0f);
                float vs = 0.f;
                #pragma unroll 8
                for (int i = 0; i < 16; ++i) {
                    const float dr = lds.a.Ytr[row][q8*16 + i] - mr;
                    const float di = lds.a.Yti[row][q8*16 + i] - mi;
                    vs = fmaf(dr, dr, vs);
                    vs = fmaf(di, di, vs);
                }
                vs += __shfl_xor(vs, 1); vs += __shfl_xor(vs, 2); vs += __shfl_xor(vs, 4);
                const float scale = 1.0f / sqrtf(vs * (1.0f/127.0f) + GEPS);

                unsigned short* dst = Yn + (size_t)(b*SEQ + q0 + row)*(2*HIDDEN) + h*DHEAD + q8*16;
                #pragma unroll
                for (int i = 0; i < 16; i += 8) {
                    __align__(16) unsigned short tre[8], tim[8];
                    #pragma unroll
                    for (int e = 0; e < 8; ++e) {
                        const int col = q8*16 + i + e;
                        const float wv_ = gnw[h*DHEAD + col];
                        const float bv_ = gnb[h*DHEAD + col];
                        tre[e] = f2bf(fmaf((lds.a.Ytr[row][col] - mr)*scale, wv_, bv_));
                        tim[e] = f2bf((lds.a.Yti[row][col] - mi)*scale*wv_);
                    }
                    *(u32x4*)(dst + i)          = *(u32x4*)tre;
                    *(u32x4*)(dst + HIDDEN + i) = *(u32x4*)tim;
                }
            }
        }
    } else {
        // ---------------- gating GEMM path (256 thr, 4 waves) ----------------
        const int gid = bid - 256;
        const int cb = ((gid & 7) << 1) | ((gid >> 3) & 1);   // 0..15
        const int mb = gid >> 4;                               // 0..31
        const int wm  = (wv >> 1)*32;   // row half
        const int wn_ = (wv & 1)*32;    // col half

        const int r0  = tid >> 2;           // 0..63
        const int seg = (tid & 3)*16;       // 0,16,32,48
        const unsigned short* ga  = Xb + (size_t)(mb*64 + r0)*HIDDEN + seg;
        const unsigned short* gbr = Bg + (size_t)(cb*64 + r0)*HIDDEN + seg;
        const unsigned short* gbi = gbr + (1u << 20);

        f32x16 aR, aI;
        #pragma unroll
        for (int e = 0; e < 16; ++e) { aR[e]=0.f; aI[e]=0.f; }

        u32x4 ra0 = *(const u32x4*)(ga);
        u32x4 ra1 = *(const u32x4*)(ga + 8);
        u32x4 rr0 = *(const u32x4*)(gbr);
        u32x4 rr1 = *(const u32x4*)(gbr + 8);
        u32x4 ri0 = *(const u32x4*)(gbi);
        u32x4 ri1 = *(const u32x4*)(gbi + 8);

        for (int kk = 0; kk < HIDDEN; kk += 64) {
            __syncthreads();
            *(u32x4*)&lds.g.As[r0][seg]     = ra0;
            *(u32x4*)&lds.g.As[r0][seg + 8] = ra1;
            *(u32x4*)&lds.g.Br[r0][seg]     = rr0;
            *(u32x4*)&lds.g.Br[r0][seg + 8] = rr1;
            *(u32x4*)&lds.g.Bi[r0][seg]     = ri0;
            *(u32x4*)&lds.g.Bi[r0][seg + 8] = ri1;
            if (kk + 64 < HIDDEN) {
                const int o = kk + 64;
                ra0 = *(const u32x4*)(ga + o);
                ra1 = *(const u32x4*)(ga + o + 8);
                rr0 = *(const u32x4*)(gbr + o);
                rr1 = *(const u32x4*)(gbr + o + 8);
                ri0 = *(const u32x4*)(gbi + o);
                ri1 = *(const u32x4*)(gbi + o + 8);
            }
            __syncthreads();
            #pragma unroll
            for (int ks = 0; ks < 4; ++ks) {
                Frag a, br, bi;
                a.u  = *(const u32x4*)&lds.g.As[wm + l31 ][ks*16 + hi*8];
                br.u = *(const u32x4*)&lds.g.Br[wn_ + l31][ks*16 + hi*8];
                bi.u = *(const u32x4*)&lds.g.Bi[wn_ + l31][ks*16 + hi*8];
                aR = __builtin_amdgcn_mfma_f32_32x32x16_bf16(a.h, br.h, aR, 0, 0, 0);
                aI = __builtin_amdgcn_mfma_f32_32x32x16_bf16(a.h, bi.h, aI, 0, 0, 0);
            }
        }

        {
            const int c = cb*64 + wn_ + l31;
            #pragma unroll
            for (int r = 0; r < 16; ++r) {
                const int row = mb*64 + wm + (r & 3) + 8*(r >> 2) + 4*hi;
                float swr, swi;
                cswish(aR[r], aI[r], swr, swi);
                const size_t o = (size_t)row*(2*HIDDEN) + c;
                Gs[o]          = f2bf(swr);
                Gs[o + HIDDEN] = f2bf(swi);
            }
        }
    }
}

// ---------------------------------------------------------------------------
// zadd: Aout = bf16(Gs + Yn), elementwise over 4M bf16
// ---------------------------------------------------------------------------
__global__ __launch_bounds__(256) void zadd_kernel(
    const unsigned short* __restrict__ Gs, const unsigned short* __restrict__ Yn,
    unsigned short* __restrict__ Aout)
{
    const size_t i = ((size_t)blockIdx.x*256 + threadIdx.x)*8;
    const u32x4 g = *(const u32x4*)&Gs[i];
    const u32x4 y = *(const u32x4*)&Yn[i];
    __align__(16) unsigned short gg[8], yy[8], t[8];
    *(u32x4*)gg = g; *(u32x4*)yy = y;
    #pragma unroll
    for (int e = 0; e < 8; ++e) t[e] = f2bf(bf2f(gg[e]) + bf2f(yy[e]));
    *(u32x4*)&Aout[i] = *(u32x4*)t;
}

// ---------------------------------------------------------------------------
// Bot[n][k] imMode=1 variant (cplx path only)
// ---------------------------------------------------------------------------
__global__ __launch_bounds__(256) void wprep_o_kernel(
    const float* __restrict__ Wore, const float* __restrict__ Woim,
    unsigned short* __restrict__ Bot, const int imMode)
{
    const int n0 = blockIdx.x*64, k0 = blockIdx.y*64;
    const float* src;
    float sign = 1.0f;
    if (!imMode) { if (k0 < HIDDEN) src = Wore; else { src = Woim; sign = -1.0f; } }
    else         { src = (k0 < HIDDEN) ? Woim : Wore; }
    const int kc = k0 & (HIDDEN-1);
    __shared__ float Ws[64][65];
    const int tid = threadIdx.x;
    #pragma unroll
    for (int it = 0; it < 4; ++it) {
        const int r = (tid >> 4) + it*16, c = (tid & 15)*4;
        const float4 v = *(const float4*)&src[(size_t)(kc + r)*HIDDEN + n0 + c];
        Ws[r][c+0] = v.x*sign; Ws[r][c+1] = v.y*sign; Ws[r][c+2] = v.z*sign; Ws[r][c+3] = v.w*sign;
    }
    __syncthreads();
    const int nl = tid >> 2, seg = (tid & 3)*16;
    __align__(16) unsigned short t[16];
    #pragma unroll
    for (int j = 0; j < 16; ++j) t[j] = f2bf(Ws[seg + j][nl]);
    u32x4* d = (u32x4*)&Bot[(size_t)(n0 + nl)*(2*HIDDEN) + k0 + seg];
    d[0] = ((u32x4*)t)[0];
    d[1] = ((u32x4*)t)[1];
}

// ---------------------------------------------------------------------------
// output GEMM (unchanged)
// ---------------------------------------------------------------------------
__global__ __launch_bounds__(256) void ogemm_kernel(
    const unsigned short* __restrict__ A,
    const unsigned short* __restrict__ Bt,
    float* __restrict__ C, const int mode)
{
    const int K = 2*HIDDEN, N = HIDDEN;
    __shared__ __align__(16) unsigned short As[128][72];
    __shared__ __align__(16) unsigned short Bs[64][72];

    const int tid = threadIdx.x;
    const int mb = blockIdx.x, nb = blockIdx.y;
    const int lane = tid & 63, w = tid >> 6;
    const int l31 = lane & 31, hi = (lane >> 5) & 1;
    const int wm = w*32;

    const int arow = tid >> 1, aseg = (tid & 1)*32;
    const int brow = tid >> 2, bseg = (tid & 3)*16;

    const unsigned short* ga = A  + (size_t)(mb*128 + arow)*K + aseg;
    const unsigned short* gb = Bt + (size_t)(nb*64 + brow)*K + bseg;

    f32x16 acc0, acc1;
    #pragma unroll
    for (int e = 0; e < 16; ++e) { acc0[e]=0.f; acc1[e]=0.f; }

    u32x4 ra0 = *(const u32x4*)(ga);
    u32x4 ra1 = *(const u32x4*)(ga + 8);
    u32x4 ra2 = *(const u32x4*)(ga + 16);
    u32x4 ra3 = *(const u32x4*)(ga + 24);
    u32x4 rb0 = *(const u32x4*)(gb);
    u32x4 rb1 = *(const u32x4*)(gb + 8);

    for (int kk = 0; kk < K; kk += 64) {
        __syncthreads();
        *(u32x4*)&As[arow][aseg]      = ra0;
        *(u32x4*)&As[arow][aseg + 8]  = ra1;
        *(u32x4*)&As[arow][aseg + 16] = ra2;
        *(u32x4*)&As[arow][aseg + 24] = ra3;
        *(u32x4*)&Bs[brow][bseg]      = rb0;
        *(u32x4*)&Bs[brow][bseg + 8]  = rb1;
        if (kk + 64 < K) {
            const int o = kk + 64;
            ra0 = *(const u32x4*)(ga + o);
            ra1 = *(const u32x4*)(ga + o + 8);
            ra2 = *(const u32x4*)(ga + o + 16);
            ra3 = *(const u32x4*)(ga + o + 24);
            rb0 = *(const u32x4*)(gb + o);
            rb1 = *(const u32x4*)(gb + o + 8);
        }
        __syncthreads();
        #pragma unroll
        for (int ks = 0; ks < 4; ++ks) {
            Frag a, b0, b1;
            a.u  = *(const u32x4*)&As[wm + l31][ks*16 + hi*8];
            b0.u = *(const u32x4*)&Bs[l31     ][ks*16 + hi*8];
            b1.u = *(const u32x4*)&Bs[l31 + 32][ks*16 + hi*8];
            acc0 = __builtin_amdgcn_mfma_f32_32x32x16_bf16(a.h, b0.h, acc0, 0, 0, 0);
            acc1 = __builtin_amdgcn_mfma_f32_32x32x16_bf16(a.h, b1.h, acc1, 0, 0, 0);
        }
    }

    const int cb = nb*64 + l31;
    #pragma unroll
    for (int r = 0; r < 16; ++r) {
        const int row = mb*128 + wm + (r & 3) + 8*(r >> 2) + 4*hi;
        if (mode == 0) {
            float* cr = C + (size_t)row*N + cb;
            cr[0]  = acc0[r];
            cr[32] = acc1[r];
        } else {
            float* cr = C + ((size_t)row*N + cb)*2 + (mode - 1);
            cr[0]  = acc0[r];
            cr[64] = acc1[r];
        }
    }
}

// ---------------------------------------------------------------------------
extern "C" void kernel_launch(void* const* d_in, const int* in_sizes, int n_in,
                              void* d_out, int out_size, void* d_ws, size_t ws_size,
                              hipStream_t stream)
{
    (void)in_sizes; (void)n_in; (void)ws_size;

    const float* X     = (const float*)d_in[0];
    const float* Wq    = (const float*)d_in[1];
    const float* Wk    = (const float*)d_in[2];
    const float* Wv    = (const float*)d_in[3];
    const float* theta = (const float*)d_in[4];
    const float* gnw   = (const float*)d_in[5];
    const float* gnb   = (const float*)d_in[6];
    const float* Wgre  = (const float*)d_in[7];
    const float* Wgim  = (const float*)d_in[8];
    const float* Wore  = (const float*)d_in[9];
    const float* Woim  = (const float*)d_in[10];

    float* ws = (float*)d_ws;
    const size_t P = (size_t)NTOK*HIDDEN;          // 2M float units

    unsigned short* Yn   = (unsigned short*)ws;          // [0,P): normed Y bf16 (8MB)
    unsigned short* Bot  = (unsigned short*)(ws + P);    // [P,1.5P): Wo^T re-mode (4MB)
    unsigned short* Qbre = (unsigned short*)(ws + 2*P);  // [2P,4P): Q/K bf16 row-major
    unsigned short* Qbim = Qbre + P;
    unsigned short* Kbre = Qbim + P;
    unsigned short* Kbim = Kbre + P;
    unsigned short* Aout = Qbre;                   // zadd output overwrites Q (dead after fat)
    unsigned short* Gs   = (unsigned short*)(ws + 4*P);  // [4P,5P): swish(G) bf16 (8MB)
    unsigned short* Vtb  = (unsigned short*)(ws + 5*P);  // [5P,5.5P): V^T bf16 (4MB)
    unsigned short* Xb   = (unsigned short*)(ws + 5*P) + P;      // [5.5P,6P)
    unsigned short* Bg   = (unsigned short*)(ws + 6*P);          // [6P,6.5P): 2 planes
    unsigned short* Wt   = (unsigned short*)(ws + 6*P) + P;      // [6.5P,7P)
    unsigned short* Boti = Wt;                     // cplx only; overwrites Wt after projm
    float* gpw = ws + 7*P;

    const int cplx = (out_size >= (int)(2*P)) ? 1 : 0;

    hipLaunchKernelGGL(prep_kernel, dim3(2176), dim3(256), 0, stream,
                       X, Wq, Wk, Wv, Wgre, Wgim, Wore, Woim,
                       gpw, Xb, Wt, Bg, Bot);
    hipLaunchKernelGGL(projm_kernel, dim3(NTOK/64, NHEADS, 3), dim3(256), 0, stream,
                       Xb, Wt, theta, Qbre, Qbim, Kbre, Kbim, Vtb);

    // fat: attention pairs (+gnorm) || gating GEMM (+swish); 256-thr blocks
    hipLaunchKernelGGL(fat_kernel, dim3(768), dim3(256), 0, stream,
                       Qbre, Qbim, Kbre, Kbim, Vtb, gpw, gnw, gnb, Yn, Xb, Bg, Gs);

    // Z = swish(G) + Yn  (writes over dead Q buffer)
    hipLaunchKernelGGL(zadd_kernel, dim3(2048), dim3(256), 0, stream, Gs, Yn, Aout);

    if (!cplx) {
        hipLaunchKernelGGL(ogemm_kernel, dim3(NTOK/128, HIDDEN/64), dim3(256), 0, stream,
                           Aout, Bot, (float*)d_out, 0);
    } else {
        hipLaunchKernelGGL(wprep_o_kernel, dim3(HIDDEN/64, 2*HIDDEN/64), dim3(256), 0, stream,
                           Wore, Woim, Boti, 1);
        hipLaunchKernelGGL(ogemm_kernel, dim3(NTOK/128, HIDDEN/64), dim3(256), 0, stream,
                           Aout, Bot, (float*)d_out, 1);
        hipLaunchKernelGGL(ogemm_kernel, dim3(NTOK/128, HIDDEN/64), dim3(256), 0, stream,
                           Aout, Boti, (float*)d_out, 2);
    }
}

// Round 22
// 115.289 us; speedup vs baseline: 1.1462x; 1.1462x over previous
//
#include <hip/hip_runtime.h>
#include <math.h>

#define BATCH  2
#define SEQ    1024
#define HIDDEN 1024
#define NHEADS 8
#define DHEAD  128
#define NTOK   (BATCH*SEQ)
#define GEPS   1e-5f

typedef float f32x16 __attribute__((ext_vector_type(16)));
typedef __bf16 bf16x8 __attribute__((ext_vector_type(8)));
typedef unsigned int u32x4 __attribute__((ext_vector_type(4)));
typedef unsigned int u32x2 __attribute__((ext_vector_type(2)));

union Frag { u32x4 u; bf16x8 h; };

__device__ __forceinline__ unsigned short f2bf(float f) {
    unsigned int u = __float_as_uint(f);
    unsigned int r = (u + 0x7FFFu + ((u >> 16) & 1u)) >> 16;
    return (unsigned short)r;
}
__device__ __forceinline__ float bf2f(unsigned short u) {
    return __uint_as_float(((unsigned int)u) << 16);
}

// complex swish: z * sigmoid(z)
__device__ __forceinline__ void cswish(float zr, float zi, float& outr, float& outi) {
    const float e = expf(-zr);
    float sg, cg;
    sincosf(zi, &sg, &cg);
    const float wr = fmaf(e, cg, 1.0f);
    const float wi = -e*sg;
    const float inv = 1.0f / fmaf(wr, wr, wi*wi);
    outr = (zr*wr + zi*wi)*inv;
    outi = (zi*wr - zr*wi)*inv;
}

// ---------------------------------------------------------------------------
// merged prep kernel
// ---------------------------------------------------------------------------
__global__ __launch_bounds__(256) void prep_kernel(
    const float* __restrict__ X,
    const float* __restrict__ Wq, const float* __restrict__ Wk, const float* __restrict__ Wv,
    const float* __restrict__ Wgre, const float* __restrict__ Wgim,
    const float* __restrict__ Wore, const float* __restrict__ Woim,
    float* __restrict__ gpow, unsigned short* __restrict__ Xb,
    unsigned short* __restrict__ Wt, unsigned short* __restrict__ Bg,
    unsigned short* __restrict__ Bot)
{
    __shared__ float Ws[64][65];
    const int id  = blockIdx.x;
    const int tid = threadIdx.x;

    if (id < 32) {
        const int h = id >> 2;
        const int k = (id & 3)*256 + tid;
        const float l = fmaf((float)h, -0.39608410317711170f, -3.46573590279972650f);
        const float gamma = 1.0f - expf(l);
        gpow[h*SEQ + k] = powf(gamma, (float)k);
    } else if (id < 1056) {
        const size_t i = ((size_t)(id - 32)*256 + tid)*8;
        const float4 a = *(const float4*)&X[i];
        const float4 b = *(const float4*)&X[i+4];
        __align__(16) unsigned short t[8] = { f2bf(a.x), f2bf(a.y), f2bf(a.z), f2bf(a.w),
                                              f2bf(b.x), f2bf(b.y), f2bf(b.z), f2bf(b.w) };
        *(u32x4*)&Xb[i] = *(u32x4*)t;
    } else if (id < 1152) {
        const int q = id - 1056;
        const int th_ = q % 24, yy = q / 24;
        const int type = th_ >> 3, h = th_ & 7;
        const int k0 = (yy >> 1)*64, n0 = (yy & 1)*64;
        const float* W = ((type == 0) ? Wq : (type == 1) ? Wk : Wv)
                         + (size_t)h*DHEAD*DHEAD;
        #pragma unroll
        for (int it = 0; it < 4; ++it) {
            const int r = (tid >> 4) + it*16, c = (tid & 15)*4;
            *(float4*)&Ws[r][c] = *(const float4*)&W[(size_t)(k0 + r)*DHEAD + n0 + c];
        }
        __syncthreads();
        const int nl = tid >> 2, seg = (tid & 3)*16;
        __align__(16) unsigned short t[16];
        #pragma unroll
        for (int j = 0; j < 16; ++j) t[j] = f2bf(Ws[seg + j][nl]);
        u32x4* d = (u32x4*)&Wt[((size_t)th_*DHEAD + n0 + nl)*DHEAD + k0 + seg];
        d[0] = ((u32x4*)t)[0];
        d[1] = ((u32x4*)t)[1];
    } else if (id < 1664) {
        const int q = id - 1152;
        const int xx = q & 31, k0 = (q >> 5)*64;
        const int plane = xx >> 4;
        const int c0 = (xx & 15)*64;
        const float* src = plane ? Wgim : Wgre;
        #pragma unroll
        for (int it = 0; it < 4; ++it) {
            const int r = (tid >> 4) + it*16, c = (tid & 15)*4;
            *(float4*)&Ws[r][c] = *(const float4*)&src[(size_t)(k0 + r)*HIDDEN + c0 + c];
        }
        __syncthreads();
        const int nl = tid >> 2, seg = (tid & 3)*16;
        __align__(16) unsigned short t[16];
        #pragma unroll
        for (int j = 0; j < 16; ++j) t[j] = f2bf(Ws[seg + j][nl]);
        u32x4* d = (u32x4*)&Bg[((size_t)plane << 20) + (size_t)(c0 + nl)*HIDDEN + k0 + seg];
        d[0] = ((u32x4*)t)[0];
        d[1] = ((u32x4*)t)[1];
    } else {
        const int q = id - 1664;
        const int n0 = (q & 15)*64, k0 = (q >> 4)*64;
        const float* src;
        float sign = 1.0f;
        if (k0 < HIDDEN) src = Wore; else { src = Woim; sign = -1.0f; }
        const int kc = k0 & (HIDDEN-1);
        #pragma unroll
        for (int it = 0; it < 4; ++it) {
            const int r = (tid >> 4) + it*16, c = (tid & 15)*4;
            const float4 v = *(const float4*)&src[(size_t)(kc + r)*HIDDEN + n0 + c];
            Ws[r][c+0] = v.x*sign; Ws[r][c+1] = v.y*sign; Ws[r][c+2] = v.z*sign; Ws[r][c+3] = v.w*sign;
        }
        __syncthreads();
        const int nl = tid >> 2, seg = (tid & 3)*16;
        __align__(16) unsigned short t[16];
        #pragma unroll
        for (int j = 0; j < 16; ++j) t[j] = f2bf(Ws[seg + j][nl]);
        u32x4* d = (u32x4*)&Bot[(size_t)(n0 + nl)*(2*HIDDEN) + k0 + seg];
        d[0] = ((u32x4*)t)[0];
        d[1] = ((u32x4*)t)[1];
    }
}

// ---------------------------------------------------------------------------
// MFMA projections + fused RoPE
// ---------------------------------------------------------------------------
__global__ __launch_bounds__(256) void projm_kernel(
    const unsigned short* __restrict__ Xb,
    const unsigned short* __restrict__ Wt,
    const float* __restrict__ theta,
    unsigned short* __restrict__ Qbre, unsigned short* __restrict__ Qbim,
    unsigned short* __restrict__ Kbre, unsigned short* __restrict__ Kbim,
    unsigned short* __restrict__ Vtb)
{
    const int tt = blockIdx.x;
    const int h  = blockIdx.y;
    const int mt = blockIdx.z;       // 0:q 1:k 2:v
    const int tid = threadIdx.x;
    const int w = tid >> 6, lane = tid & 63;
    const int th = w >> 1, nh = w & 1;
    const int l31 = lane & 31, hi = (lane >> 5) & 1;

    Frag A[8];
    {
        const unsigned short* xa = Xb + (size_t)(tt*64 + th*32 + l31)*HIDDEN
                                   + h*DHEAD + 8*hi;
        #pragma unroll
        for (int ks = 0; ks < 8; ++ks) A[ks].u = *(const u32x4*)(xa + 16*ks);
    }

    const unsigned short* wb = Wt + (size_t)(mt*NHEADS + h)*DHEAD*DHEAD;

    #pragma unroll
    for (int nt = 0; nt < 2; ++nt) {
        const int n0 = nh*64 + nt*32;
        const int n  = n0 + l31;

        Frag B[8];
        const unsigned short* wp = wb + (size_t)n*DHEAD + 8*hi;
        #pragma unroll
        for (int ks = 0; ks < 8; ++ks) B[ks].u = *(const u32x4*)(wp + 16*ks);

        f32x16 acc;
        #pragma unroll
        for (int e = 0; e < 16; ++e) acc[e] = 0.f;
        #pragma unroll
        for (int ks = 0; ks < 8; ++ks)
            acc = __builtin_amdgcn_mfma_f32_32x32x16_bf16(A[ks].h, B[ks].h, acc, 0, 0, 0);

        if (mt == 2) {
            const int b2  = (tt*64) >> 10;
            const int bh2 = b2*NHEADS + h;
            const int sbase = (tt*64 + th*32) & (SEQ-1);
            unsigned short* vdst = Vtb + ((size_t)(bh2*DHEAD + n))*SEQ + sbase;
            #pragma unroll
            for (int g2 = 0; g2 < 4; ++g2) {
                const int s0 = 8*g2 + 4*hi;
                __align__(8) unsigned short t4[4];
                #pragma unroll
                for (int j = 0; j < 4; ++j) t4[j] = f2bf(acc[g2*4 + j]);
                *(u32x2*)(vdst + s0) = *(u32x2*)t4;
            }
        } else {
            const float thv = theta[h*DHEAD + n];
            unsigned short* pre = (mt == 0) ? Qbre : Kbre;
            unsigned short* pim = (mt == 0) ? Qbim : Kbim;
            const float sgn = (mt == 0) ? 1.0f : -1.0f;
            #pragma unroll
            for (int r = 0; r < 16; ++r) {
                const int row = (r & 3) + 8*(r >> 2) + 4*hi;
                const int tok = tt*64 + th*32 + row;
                const float np1 = (float)((tok & (SEQ-1)) + 1);
                float s, c;
                sincosf(np1*thv, &s, &c);
                const size_t g = (size_t)tok*HIDDEN + h*DHEAD + n;
                pre[g] = f2bf(acc[r]*c);
                pim[g] = f2bf(acc[r]*s*sgn);
            }
        }
    }
}

// ---------------------------------------------------------------------------
// FAT kernel: blocks [0,512) = attention + fused group-norm -> Yn;
//             blocks [512,1024) = gating GEMM -> swish -> Gs.
// attn m-loop: K regs for m+1 reloaded immediately AFTER QK^T(m).
// ---------------------------------------------------------------------------
#define CVTPK(dst, a, b) asm("v_cvt_pk_bf16_f32 %0, %1, %2" : "=v"(dst) : "v"(a), "v"(b))
#define SWAP32(x, y)     asm("v_permlane32_swap_b32 %0, %1" : "+v"(x), "+v"(y))

union FatLds {
    struct { float Ytr[32][133]; float Yti[32][133]; } a;
    struct { unsigned short As[64][68]; unsigned short Br[64][68]; unsigned short Bi[64][68]; } g;
};

__global__ __launch_bounds__(128) void fat_kernel(
    const unsigned short* __restrict__ Qbre, const unsigned short* __restrict__ Qbim,
    const unsigned short* __restrict__ Kbre, const unsigned short* __restrict__ Kbim,
    const unsigned short* __restrict__ Vtb,  const float* __restrict__ gpow,
    const float* __restrict__ gnw, const float* __restrict__ gnb,
    unsigned short* __restrict__ Yn,
    const unsigned short* __restrict__ Xb, const unsigned short* __restrict__ Bg,
    unsigned short* __restrict__ Gs)
{
    __shared__ FatLds lds;

    const int bid  = blockIdx.x;
    const int tid  = threadIdx.x;
    const int lane = tid & 63;
    const int wv   = tid >> 6;
    const int l31 = lane & 31, hi = (lane >> 5) & 1;

    if (bid < 512) {
        // ---------------- attention path ----------------
        const int id = bid;
        const int bh = ((id & 7) << 1) | ((id >> 3) & 1);
        const int qt = id >> 4;

        const int b = bh >> 3, h = bh & 7;
        const int q0 = qt * 32;
        const size_t bhoff = (size_t)b*SEQ*HIDDEN + h*DHEAD;
        const float* gp = gpow + h*SEQ;

        int   crw[16];
        float ginv[16];
        #pragma unroll
        for (int r = 0; r < 16; ++r) {
            const int cr = (r & 3) + 8*(r >> 2) + 4*hi;
            crw[r] = cr;
            ginv[r] = 1.0f / gp[cr];
        }

        Frag Qr[8], Qi[8];
        {
            const unsigned short* qr = Qbre + bhoff + (size_t)(q0 + l31)*HIDDEN + 8*hi;
            const unsigned short* qi = Qbim + bhoff + (size_t)(q0 + l31)*HIDDEN + 8*hi;
            #pragma unroll
            for (int ks = 0; ks < 8; ++ks) {
                Qr[ks].u = *(const u32x4*)(qr + 16*ks);
                Qi[ks].u = *(const u32x4*)(qi + 16*ks);
            }
        }

        f32x16 Yr[4], Yi[4];
        #pragma unroll
        for (int dt = 0; dt < 4; ++dt)
            #pragma unroll
            for (int e = 0; e < 16; ++e) { Yr[dt][e] = 0.f; Yi[dt][e] = 0.f; }

        const int nm   = qt + 1;
        const int half = (nm + 1) >> 1;
        const int mlo  = wv ? half : 0;
        const int mhi  = wv ? nm   : half;

        // K single-buffer with early reload: prologue load for m = mlo
        Frag Kr[8], Ki[8];
        if (mlo < mhi) {
            const int kv0p = mlo*32;
            const unsigned short* kr_ = Kbre + bhoff + (size_t)(kv0p + l31)*HIDDEN + 8*hi;
            const unsigned short* ki_ = Kbim + bhoff + (size_t)(kv0p + l31)*HIDDEN + 8*hi;
            #pragma unroll
            for (int ks = 0; ks < 8; ++ks) {
                Kr[ks].u = *(const u32x4*)(kr_ + 16*ks);
                Ki[ks].u = *(const u32x4*)(ki_ + 16*ks);
            }
        }

        #pragma unroll 1
        for (int m = mlo; m < mhi; ++m) {
            const int kv0 = m*32;

            // V loads for this iteration (used after QK^T -> latency covered)
            Frag Vf[4][2];
            #pragma unroll
            for (int dt = 0; dt < 4; ++dt)
                #pragma unroll
                for (int ks2 = 0; ks2 < 2; ++ks2)
                    Vf[dt][ks2].u = *(const u32x4*)(Vtb + ((size_t)(bh*DHEAD + dt*32 + l31))*SEQ
                                                    + kv0 + 16*ks2 + 8*hi);

            const int  base = 32*(qt - m) + l31;
            const float g1  = gp[base];

            // QK^T with current K regs
            f32x16 SR, SI;
            #pragma unroll
            for (int e = 0; e < 16; ++e) { SR[e] = 0.f; SI[e] = 0.f; }
            #pragma unroll
            for (int ks = 0; ks < 8; ++ks) {
                Frag Qin;
                #pragma unroll
                for (int e = 0; e < 4; ++e) Qin.u[e] = Qi[ks].u[e] ^ 0x80008000u;
                SR = __builtin_amdgcn_mfma_f32_32x32x16_bf16(Kr[ks].h, Qr[ks].h, SR, 0, 0, 0);
                SI = __builtin_amdgcn_mfma_f32_32x32x16_bf16(Kr[ks].h, Qi[ks].h, SI, 0, 0, 0);
                SR = __builtin_amdgcn_mfma_f32_32x32x16_bf16(Ki[ks].h, Qin.h, SR, 0, 0, 0);
                SI = __builtin_amdgcn_mfma_f32_32x32x16_bf16(Ki[ks].h, Qr[ks].h, SI, 0, 0, 0);
            }

            // K regs dead: reload for m+1 NOW (latency hides under P+PV below)
            if (m + 1 < mhi) {
                const int kn = (m + 1)*32;
                const unsigned short* kr_ = Kbre + bhoff + (size_t)(kn + l31)*HIDDEN + 8*hi;
                const unsigned short* ki_ = Kbim + bhoff + (size_t)(kn + l31)*HIDDEN + 8*hi;
                #pragma unroll
                for (int ks = 0; ks < 8; ++ks) {
                    Kr[ks].u = *(const u32x4*)(kr_ + 16*ks);
                    Ki[ks].u = *(const u32x4*)(ki_ + 16*ks);
                }
            }

            float pr[16], pi[16];
            #pragma unroll
            for (int r = 0; r < 16; ++r) {
                const float w = (base >= crw[r]) ? g1*ginv[r] : 0.0f;
                pr[r] = SR[r]*w;
                pi[r] = SI[r]*w;
            }

            Frag PR[2], PI[2];
            #pragma unroll
            for (int ks2 = 0; ks2 < 2; ++ks2) {
                const int o = ks2*8;
                unsigned int a0, b0, a1, b1;
                CVTPK(a0, pr[o+0], pr[o+1]);
                CVTPK(b0, pr[o+4], pr[o+5]);
                SWAP32(a0, b0);
                CVTPK(a1, pr[o+2], pr[o+3]);
                CVTPK(b1, pr[o+6], pr[o+7]);
                SWAP32(a1, b1);
                PR[ks2].u[0] = a0; PR[ks2].u[1] = a1; PR[ks2].u[2] = b0; PR[ks2].u[3] = b1;
                CVTPK(a0, pi[o+0], pi[o+1]);
                CVTPK(b0, pi[o+4], pi[o+5]);
                SWAP32(a0, b0);
                CVTPK(a1, pi[o+2], pi[o+3]);
                CVTPK(b1, pi[o+6], pi[o+7]);
                SWAP32(a1, b1);
                PI[ks2].u[0] = a0; PI[ks2].u[1] = a1; PI[ks2].u[2] = b0; PI[ks2].u[3] = b1;
            }

            #pragma unroll
            for (int dt = 0; dt < 4; ++dt) {
                Yr[dt] = __builtin_amdgcn_mfma_f32_32x32x16_bf16(Vf[dt][0].h, PR[0].h, Yr[dt], 0, 0, 0);
                Yr[dt] = __builtin_amdgcn_mfma_f32_32x32x16_bf16(Vf[dt][1].h, PR[1].h, Yr[dt], 0, 0, 0);
                Yi[dt] = __builtin_amdgcn_mfma_f32_32x32x16_bf16(Vf[dt][0].h, PI[0].h, Yi[dt], 0, 0, 0);
                Yi[dt] = __builtin_amdgcn_mfma_f32_32x32x16_bf16(Vf[dt][1].h, PI[1].h, Yi[dt], 0, 0, 0);
            }
        }

        if (wv == 0) {
            #pragma unroll
            for (int dt = 0; dt < 4; ++dt)
                #pragma unroll
                for (int r = 0; r < 16; ++r) {
                    lds.a.Ytr[l31][dt*32 + crw[r]] = Yr[dt][r];
                    lds.a.Yti[l31][dt*32 + crw[r]] = Yi[dt][r];
                }
        }
        __syncthreads();
        if (wv == 1) {
            #pragma unroll
            for (int dt = 0; dt < 4; ++dt)
                #pragma unroll
                for (int r = 0; r < 16; ++r) {
                    lds.a.Ytr[l31][dt*32 + crw[r]] += Yr[dt][r];
                    lds.a.Yti[l31][dt*32 + crw[r]] += Yi[dt][r];
                }
        }
        __syncthreads();

        {
            const int row = tid >> 2;
            const int q4  = tid & 3;
            float sr = 0.f, si = 0.f;
            #pragma unroll 8
            for (int i = 0; i < 32; ++i) {
                sr += lds.a.Ytr[row][q4*32 + i];
                si += lds.a.Yti[row][q4*32 + i];
            }
            sr += __shfl_xor(sr, 1); sr += __shfl_xor(sr, 2);
            si += __shfl_xor(si, 1); si += __shfl_xor(si, 2);
            const float mr = sr * (1.0f/128.0f), mi = si * (1.0f/128.0f);
            float vs = 0.f;
            #pragma unroll 8
            for (int i = 0; i < 32; ++i) {
                const float dr = lds.a.Ytr[row][q4*32 + i] - mr;
                const float di = lds.a.Yti[row][q4*32 + i] - mi;
                vs = fmaf(dr, dr, vs);
                vs = fmaf(di, di, vs);
            }
            vs += __shfl_xor(vs, 1); vs += __shfl_xor(vs, 2);
            const float scale = 1.0f / sqrtf(vs * (1.0f/127.0f) + GEPS);

            unsigned short* dst = Yn + (size_t)(b*SEQ + q0 + row)*(2*HIDDEN) + h*DHEAD + q4*32;
            #pragma unroll
            for (int i = 0; i < 32; i += 8) {
                __align__(16) unsigned short tre[8], tim[8];
                #pragma unroll
                for (int e = 0; e < 8; ++e) {
                    const int col = q4*32 + i + e;
                    const float wv_ = gnw[h*DHEAD + col];
                    const float bv_ = gnb[h*DHEAD + col];
                    tre[e] = f2bf(fmaf((lds.a.Ytr[row][col] - mr)*scale, wv_, bv_));
                    tim[e] = f2bf((lds.a.Yti[row][col] - mi)*scale*wv_);
                }
                *(u32x4*)(dst + i)          = *(u32x4*)tre;
                *(u32x4*)(dst + HIDDEN + i) = *(u32x4*)tim;
            }
        }
    } else {
        // ---------------- gating GEMM path: G = Xb @ Wg, swish -> Gs --------
        const int gid = bid - 512;
        const int cb = ((gid & 7) << 1) | ((gid >> 3) & 1);   // 0..15
        const int mb = gid >> 4;                               // 0..31
        const int wm = wv*32;

        const int r0   = tid >> 2;          // 0..31
        const int seg  = (tid & 3)*16;      // 0,16,32,48
        const unsigned short* ga0  = Xb + (size_t)(mb*64 + r0)*HIDDEN + seg;
        const unsigned short* ga1  = ga0 + (size_t)32*HIDDEN;
        const unsigned short* gbr0 = Bg + (size_t)(cb*64 + r0)*HIDDEN + seg;
        const unsigned short* gbr1 = gbr0 + (size_t)32*HIDDEN;
        const unsigned short* gbi0 = gbr0 + (1u << 20);
        const unsigned short* gbi1 = gbr1 + (1u << 20);

        f32x16 aR0, aR1, aI0, aI1;
        #pragma unroll
        for (int e = 0; e < 16; ++e) { aR0[e]=0.f; aR1[e]=0.f; aI0[e]=0.f; aI1[e]=0.f; }

        u32x4 ra0 = *(const u32x4*)(ga0);
        u32x4 ra1 = *(const u32x4*)(ga0 + 8);
        u32x4 ra2 = *(const u32x4*)(ga1);
        u32x4 ra3 = *(const u32x4*)(ga1 + 8);
        u32x4 rr0 = *(const u32x4*)(gbr0);
        u32x4 rr1 = *(const u32x4*)(gbr0 + 8);
        u32x4 rr2 = *(const u32x4*)(gbr1);
        u32x4 rr3 = *(const u32x4*)(gbr1 + 8);
        u32x4 ri0 = *(const u32x4*)(gbi0);
        u32x4 ri1 = *(const u32x4*)(gbi0 + 8);
        u32x4 ri2 = *(const u32x4*)(gbi1);
        u32x4 ri3 = *(const u32x4*)(gbi1 + 8);

        for (int kk = 0; kk < HIDDEN; kk += 64) {
            __syncthreads();
            *(u32x4*)&lds.g.As[r0     ][seg]     = ra0;
            *(u32x4*)&lds.g.As[r0     ][seg + 8] = ra1;
            *(u32x4*)&lds.g.As[r0 + 32][seg]     = ra2;
            *(u32x4*)&lds.g.As[r0 + 32][seg + 8] = ra3;
            *(u32x4*)&lds.g.Br[r0     ][seg]     = rr0;
            *(u32x4*)&lds.g.Br[r0     ][seg + 8] = rr1;
            *(u32x4*)&lds.g.Br[r0 + 32][seg]     = rr2;
            *(u32x4*)&lds.g.Br[r0 + 32][seg + 8] = rr3;
            *(u32x4*)&lds.g.Bi[r0     ][seg]     = ri0;
            *(u32x4*)&lds.g.Bi[r0     ][seg + 8] = ri1;
            *(u32x4*)&lds.g.Bi[r0 + 32][seg]     = ri2;
            *(u32x4*)&lds.g.Bi[r0 + 32][seg + 8] = ri3;
            if (kk + 64 < HIDDEN) {
                const int o = kk + 64;
                ra0 = *(const u32x4*)(ga0 + o);
                ra1 = *(const u32x4*)(ga0 + o + 8);
                ra2 = *(const u32x4*)(ga1 + o);
                ra3 = *(const u32x4*)(ga1 + o + 8);
                rr0 = *(const u32x4*)(gbr0 + o);
                rr1 = *(const u32x4*)(gbr0 + o + 8);
                rr2 = *(const u32x4*)(gbr1 + o);
                rr3 = *(const u32x4*)(gbr1 + o + 8);
                ri0 = *(const u32x4*)(gbi0 + o);
                ri1 = *(const u32x4*)(gbi0 + o + 8);
                ri2 = *(const u32x4*)(gbi1 + o);
                ri3 = *(const u32x4*)(gbi1 + o + 8);
            }
            __syncthreads();
            #pragma unroll
            for (int ks = 0; ks < 4; ++ks) {
                Frag a, br0, br1, bi0, bi1;
                a.u   = *(const u32x4*)&lds.g.As[wm + l31][ks*16 + hi*8];
                br0.u = *(const u32x4*)&lds.g.Br[l31     ][ks*16 + hi*8];
                br1.u = *(const u32x4*)&lds.g.Br[l31 + 32][ks*16 + hi*8];
                bi0.u = *(const u32x4*)&lds.g.Bi[l31     ][ks*16 + hi*8];
                bi1.u = *(const u32x4*)&lds.g.Bi[l31 + 32][ks*16 + hi*8];
                aR0 = __builtin_amdgcn_mfma_f32_32x32x16_bf16(a.h, br0.h, aR0, 0, 0, 0);
                aR1 = __builtin_amdgcn_mfma_f32_32x32x16_bf16(a.h, br1.h, aR1, 0, 0, 0);
                aI0 = __builtin_amdgcn_mfma_f32_32x32x16_bf16(a.h, bi0.h, aI0, 0, 0, 0);
                aI1 = __builtin_amdgcn_mfma_f32_32x32x16_bf16(a.h, bi1.h, aI1, 0, 0, 0);
            }
        }

        #pragma unroll
        for (int ct = 0; ct < 2; ++ct) {
            const f32x16& cr = ct ? aR1 : aR0;
            const f32x16& ci = ct ? aI1 : aI0;
            const int c = cb*64 + ct*32 + l31;
            #pragma unroll
            for (int r = 0; r < 16; ++r) {
                const int row = mb*64 + wm + (r & 3) + 8*(r >> 2) + 4*hi;
                float swr, swi;
                cswish(cr[r], ci[r], swr, swi);
                const size_t o = (size_t)row*(2*HIDDEN) + c;
                Gs[o]          = f2bf(swr);
                Gs[o + HIDDEN] = f2bf(swi);
            }
        }
    }
}

// ---------------------------------------------------------------------------
// zadd: Aout = bf16(Gs + Yn), elementwise over 4M bf16
// ---------------------------------------------------------------------------
__global__ __launch_bounds__(256) void zadd_kernel(
    const unsigned short* __restrict__ Gs, const unsigned short* __restrict__ Yn,
    unsigned short* __restrict__ Aout)
{
    const size_t i = ((size_t)blockIdx.x*256 + threadIdx.x)*8;
    const u32x4 g = *(const u32x4*)&Gs[i];
    const u32x4 y = *(const u32x4*)&Yn[i];
    __align__(16) unsigned short gg[8], yy[8], t[8];
    *(u32x4*)gg = g; *(u32x4*)yy = y;
    #pragma unroll
    for (int e = 0; e < 8; ++e) t[e] = f2bf(bf2f(gg[e]) + bf2f(yy[e]));
    *(u32x4*)&Aout[i] = *(u32x4*)t;
}

// ---------------------------------------------------------------------------
// Bot[n][k] imMode=1 variant (cplx path only)
// ---------------------------------------------------------------------------
__global__ __launch_bounds__(256) void wprep_o_kernel(
    const float* __restrict__ Wore, const float* __restrict__ Woim,
    unsigned short* __restrict__ Bot, const int imMode)
{
    const int n0 = blockIdx.x*64, k0 = blockIdx.y*64;
    const float* src;
    float sign = 1.0f;
    if (!imMode) { if (k0 < HIDDEN) src = Wore; else { src = Woim; sign = -1.0f; } }
    else         { src = (k0 < HIDDEN) ? Woim : Wore; }
    const int kc = k0 & (HIDDEN-1);
    __shared__ float Ws[64][65];
    const int tid = threadIdx.x;
    #pragma unroll
    for (int it = 0; it < 4; ++it) {
        const int r = (tid >> 4) + it*16, c = (tid & 15)*4;
        const float4 v = *(const float4*)&src[(size_t)(kc + r)*HIDDEN + n0 + c];
        Ws[r][c+0] = v.x*sign; Ws[r][c+1] = v.y*sign; Ws[r][c+2] = v.z*sign; Ws[r][c+3] = v.w*sign;
    }
    __syncthreads();
    const int nl = tid >> 2, seg = (tid & 3)*16;
    __align__(16) unsigned short t[16];
    #pragma unroll
    for (int j = 0; j < 16; ++j) t[j] = f2bf(Ws[seg + j][nl]);
    u32x4* d = (u32x4*)&Bot[(size_t)(n0 + nl)*(2*HIDDEN) + k0 + seg];
    d[0] = ((u32x4*)t)[0];
    d[1] = ((u32x4*)t)[1];
}

// ---------------------------------------------------------------------------
// output GEMM
// ---------------------------------------------------------------------------
__global__ __launch_bounds__(256) void ogemm_kernel(
    const unsigned short* __restrict__ A,
    const unsigned short* __restrict__ Bt,
    float* __restrict__ C, const int mode)
{
    const int K = 2*HIDDEN, N = HIDDEN;
    __shared__ __align__(16) unsigned short As[128][72];
    __shared__ __align__(16) unsigned short Bs[64][72];

    const int tid = threadIdx.x;
    const int mb = blockIdx.x, nb = blockIdx.y;
    const int lane = tid & 63, w = tid >> 6;
    const int l31 = lane & 31, hi = (lane >> 5) & 1;
    const int wm = w*32;

    const int arow = tid >> 1, aseg = (tid & 1)*32;
    const int brow = tid >> 2, bseg = (tid & 3)*16;

    const unsigned short* ga = A  + (size_t)(mb*128 + arow)*K + aseg;
    const unsigned short* gb = Bt + (size_t)(nb*64 + brow)*K + bseg;

    f32x16 acc0, acc1;
    #pragma unroll
    for (int e = 0; e < 16; ++e) { acc0[e]=0.f; acc1[e]=0.f; }

    u32x4 ra0 = *(const u32x4*)(ga);
    u32x4 ra1 = *(const u32x4*)(ga + 8);
    u32x4 ra2 = *(const u32x4*)(ga + 16);
    u32x4 ra3 = *(const u32x4*)(ga + 24);
    u32x4 rb0 = *(const u32x4*)(gb);
    u32x4 rb1 = *(const u32x4*)(gb + 8);

    for (int kk = 0; kk < K; kk += 64) {
        __syncthreads();
        *(u32x4*)&As[arow][aseg]      = ra0;
        *(u32x4*)&As[arow][aseg + 8]  = ra1;
        *(u32x4*)&As[arow][aseg + 16] = ra2;
        *(u32x4*)&As[arow][aseg + 24] = ra3;
        *(u32x4*)&Bs[brow][bseg]      = rb0;
        *(u32x4*)&Bs[brow][bseg + 8]  = rb1;
        if (kk + 64 < K) {
            const int o = kk + 64;
            ra0 = *(const u32x4*)(ga + o);
            ra1 = *(const u32x4*)(ga + o + 8);
            ra2 = *(const u32x4*)(ga + o + 16);
            ra3 = *(const u32x4*)(ga + o + 24);
            rb0 = *(const u32x4*)(gb + o);
            rb1 = *(const u32x4*)(gb + o + 8);
        }
        __syncthreads();
        #pragma unroll
        for (int ks = 0; ks < 4; ++ks) {
            Frag a, b0, b1;
            a.u  = *(const u32x4*)&As[wm + l31][ks*16 + hi*8];
            b0.u = *(const u32x4*)&Bs[l31     ][ks*16 + hi*8];
            b1.u = *(const u32x4*)&Bs[l31 + 32][ks*16 + hi*8];
            acc0 = __builtin_amdgcn_mfma_f32_32x32x16_bf16(a.h, b0.h, acc0, 0, 0, 0);
            acc1 = __builtin_amdgcn_mfma_f32_32x32x16_bf16(a.h, b1.h, acc1, 0, 0, 0);
        }
    }

    const int cb = nb*64 + l31;
    #pragma unroll
    for (int r = 0; r < 16; ++r) {
        const int row = mb*128 + wm + (r & 3) + 8*(r >> 2) + 4*hi;
        if (mode == 0) {
            float* cr = C + (size_t)row*N + cb;
            cr[0]  = acc0[r];
            cr[32] = acc1[r];
        } else {
            float* cr = C + ((size_t)row*N + cb)*2 + (mode - 1);
            cr[0]  = acc0[r];
            cr[64] = acc1[r];
        }
    }
}

// ---------------------------------------------------------------------------
extern "C" void kernel_launch(void* const* d_in, const int* in_sizes, int n_in,
                              void* d_out, int out_size, void* d_ws, size_t ws_size,
                              hipStream_t stream)
{
    (void)in_sizes; (void)n_in; (void)ws_size;

    const float* X     = (const float*)d_in[0];
    const float* Wq    = (const float*)d_in[1];
    const float* Wk    = (const float*)d_in[2];
    const float* Wv    = (const float*)d_in[3];
    const float* theta = (const float*)d_in[4];
    const float* gnw   = (const float*)d_in[5];
    const float* gnb   = (const float*)d_in[6];
    const float* Wgre  = (const float*)d_in[7];
    const float* Wgim  = (const float*)d_in[8];
    const float* Wore  = (const float*)d_in[9];
    const float* Woim  = (const float*)d_in[10];

    float* ws = (float*)d_ws;
    const size_t P = (size_t)NTOK*HIDDEN;          // 2M float units

    unsigned short* Yn   = (unsigned short*)ws;          // [0,P): normed Y bf16 (8MB)
    unsigned short* Bot  = (unsigned short*)(ws + P);    // [P,1.5P): Wo^T re-mode (4MB)
    unsigned short* Qbre = (unsigned short*)(ws + 2*P);  // [2P,4P): Q/K bf16 row-major
    unsigned short* Qbim = Qbre + P;
    unsigned short* Kbre = Qbim + P;
    unsigned short* Kbim = Kbre + P;
    unsigned short* Aout = Qbre;                   // zadd output overwrites Q (dead after fat)
    unsigned short* Gs   = (unsigned short*)(ws + 4*P);  // [4P,5P): swish(G) bf16 (8MB)
    unsigned short* Vtb  = (unsigned short*)(ws + 5*P);  // [5P,5.5P): V^T bf16 (4MB)
    unsigned short* Xb   = (unsigned short*)(ws + 5*P) + P;      // [5.5P,6P)
    unsigned short* Bg   = (unsigned short*)(ws + 6*P);          // [6P,6.5P): 2 planes
    unsigned short* Wt   = (unsigned short*)(ws + 6*P) + P;      // [6.5P,7P)
    unsigned short* Boti = Wt;                     // cplx only; overwrites Wt after projm
    float* gpw = ws + 7*P;

    const int cplx = (out_size >= (int)(2*P)) ? 1 : 0;

    hipLaunchKernelGGL(prep_kernel, dim3(2176), dim3(256), 0, stream,
                       X, Wq, Wk, Wv, Wgre, Wgim, Wore, Woim,
                       gpw, Xb, Wt, Bg, Bot);
    hipLaunchKernelGGL(projm_kernel, dim3(NTOK/64, NHEADS, 3), dim3(256), 0, stream,
                       Xb, Wt, theta, Qbre, Qbim, Kbre, Kbim, Vtb);

    // fat: attention (+gnorm) || gating GEMM (+swish)
    hipLaunchKernelGGL(fat_kernel, dim3(1024), dim3(128), 0, stream,
                       Qbre, Qbim, Kbre, Kbim, Vtb, gpw, gnw, gnb, Yn, Xb, Bg, Gs);

    // Z = swish(G) + Yn  (writes over dead Q buffer)
    hipLaunchKernelGGL(zadd_kernel, dim3(2048), dim3(256), 0, stream, Gs, Yn, Aout);

    if (!cplx) {
        hipLaunchKernelGGL(ogemm_kernel, dim3(NTOK/128, HIDDEN/64), dim3(256), 0, stream,
                           Aout, Bot, (float*)d_out, 0);
    } else {
        hipLaunchKernelGGL(wprep_o_kernel, dim3(HIDDEN/64, 2*HIDDEN/64), dim3(256), 0, stream,
                           Wore, Woim, Boti, 1);
        hipLaunchKernelGGL(ogemm_kernel, dim3(NTOK/128, HIDDEN/64), dim3(256), 0, stream,
                           Aout, Bot, (float*)d_out, 1);
        hipLaunchKernelGGL(ogemm_kernel, dim3(NTOK/128, HIDDEN/64), dim3(256), 0, stream,
                           Aout, Boti, (float*)d_out, 2);
    }
}